// Round 8
// baseline (248.311 us; speedup 1.0000x reference)
//
#include <hip/hip_runtime.h>

#define D 128
#define CAP 3072        // coarse-bucket capacity (mean 2046, sigma ~45)

typedef __attribute__((ext_vector_type(8))) short short8;   // 8 bf16 (4 VGPRs)
typedef __attribute__((ext_vector_type(4))) float f32x4;    // MFMA acc

// bf16 helpers: packed storage = little-endian pairs in a uint (elem 2i = lo)
__device__ __forceinline__ float blo(unsigned w) { return __uint_as_float(w << 16); }
__device__ __forceinline__ float bhi(unsigned w) { return __uint_as_float(w & 0xFFFF0000u); }
__device__ __forceinline__ unsigned bpack(float a, float b) {   // RNE
    unsigned ua = __float_as_uint(a), ub = __float_as_uint(b);
    ua += 0x7FFFu + ((ua >> 16) & 1u);
    ub += 0x7FFFu + ((ub >> 16) & 1u);
    return (ua >> 16) | (ub & 0xFFFF0000u);
}

// ---------------------------------------------------------------------------
// setup_mega (r3-proven, byte-identical): ONE dispatch for prep + bucket1:
//   blocks [0, B1B)        : bucket1 (coarse sort, 4096 edges/block,
//                            64B-padded claim counters)
//   blocks [B1B, +CB)      : conv_x  (fp32 x -> bf16 x-part of A1)
//   blocks [.., +128)      : prep_w  (Wt bf16, 64 blocks per layer)
//   block  next            : prep_c  (cvec, both layers)
//   blocks [.., +RB)       : conv_rel (rel fp32 -> bf16)
// coarseCnt must be zeroed (hipMemsetAsync) before this kernel.
// ---------------------------------------------------------------------------
__global__ __launch_bounds__(256) void setup_mega(
    const float* __restrict__ x,
    const int* __restrict__ srcA, const int* __restrict__ dstA,
    const int* __restrict__ etA,
    const float* __restrict__ WI1, const float* __restrict__ WO1,
    const float* __restrict__ WI2, const float* __restrict__ WO2,
    const float* __restrict__ rel1, const float* __restrict__ rel2,
    const float* __restrict__ b1, const float* __restrict__ b2,
    unsigned* __restrict__ A1,
    unsigned* __restrict__ Wt1, unsigned* __restrict__ Wt2,
    float* __restrict__ c1, float* __restrict__ c2,
    unsigned* __restrict__ rb1, unsigned* __restrict__ rb2,
    int* __restrict__ coarseCnt, unsigned* __restrict__ bulk,
    int N, int E, int relHalf, int nCoarse) {
    int tid = threadIdx.x;
    int bx = blockIdx.x;
    const int B1B = (E + 4095) / 4096;

    if (bx < B1B) {                               // ---- bucket1 ----
        __shared__ unsigned pay[4096];
        __shared__ unsigned short ck[4096];
        __shared__ int hist[400];
        __shared__ int base[400];
        int e0 = bx * 4096;
        int cnt = E - e0; if (cnt > 4096) cnt = 4096;
        for (int i = tid; i < nCoarse; i += 256) hist[i] = 0;
        __syncthreads();
        for (int i = tid; i < cnt; i += 256) {
            int e = e0 + i;
            int d = dstA[e];
            pay[i] = (unsigned)srcA[e] | ((unsigned)etA[e] << 17) | ((unsigned)(d & 127) << 25);
            int c = d >> 7;
            ck[i] = (unsigned short)c;
            atomicAdd(&hist[c], 1);
        }
        __syncthreads();
        for (int i = tid; i < nCoarse; i += 256) {
            int h = hist[i];
            base[i] = (h > 0) ? (i * CAP + atomicAdd(&coarseCnt[i * 16], h)) : 0;
            hist[i] = 0;
        }
        __syncthreads();
        for (int i = tid; i < cnt; i += 256) {
            int c = ck[i];
            int pos = base[c] + atomicAdd(&hist[c], 1);
            bulk[pos] = pay[i];
        }
        return;
    }
    bx -= B1B;
    const int CB = (N * 32 + 255) / 256;
    if (bx < CB) {                                // ---- conv_x ----
        int idx = bx * 256 + tid;
        if (idx < N * 32) {
            int n = idx >> 5, q = idx & 31;
            float4 v = ((const float4*)x)[idx];
            uint2 o;
            o.x = bpack(v.x, v.y);
            o.y = bpack(v.z, v.w);
            *(uint2*)(A1 + (size_t)n * 128 + 64 + q * 2) = o;
        }
        return;
    }
    bx -= CB;
    if (bx < 128) {                               // ---- prep_w ----
        int layer = bx >> 6;
        const float* WI = layer ? WI2 : WI1;
        const float* WO = layer ? WO2 : WO1;
        unsigned* Wt = layer ? Wt2 : Wt1;
        int idx = (bx & 63) * 256 + tid;          // 0..16383
        int j = idx >> 7;
        int kk = idx & 127;
        int k0 = kk * 2;
        float a, b;
        if (k0 < D) {
            a = WI[j * D + k0];
            b = WI[j * D + k0 + 1];
        } else {
            int kx = k0 - D;
            a = WI[j * D + kx]     + WO[j * D + kx];
            b = WI[j * D + kx + 1] + WO[j * D + kx + 1];
        }
        Wt[idx] = bpack(a, b);
        return;
    }
    bx -= 128;
    if (bx == 0) {                                // ---- prep_c ----
        int layer = tid >> 7;
        int j = tid & (D - 1);
        const float* WI = layer ? WI2 : WI1;
        const float* b  = layer ? b2  : b1;
        const float* rl = layer ? rel2 : rel1;
        float s = b[j];
        for (int k = 0; k < D; ++k) s = fmaf(-WI[j * D + k], rl[k], s);
        (layer ? c2 : c1)[j] = s;
        return;
    }
    bx -= 1;
    {                                             // ---- conv_rel ----
        int idx = bx * 256 + tid;
        if (idx < 2 * relHalf) {
            const float* src = (idx < relHalf) ? rel1 : rel2;
            unsigned* dst = (idx < relHalf) ? rb1 : rb2;
            int k = (idx < relHalf) ? idx : idx - relHalf;
            float4 v = ((const float4*)src)[k];
            uint2 o;
            o.x = bpack(v.x, v.y);
            o.y = bpack(v.z, v.w);
            *(uint2*)(dst + (size_t)k * 2) = o;
        }
    }
}

// ---------------------------------------------------------------------------
// bucket2 (scan fused, r6/r7-proven): one block per coarse bucket. Reduces
// the padded coarse counters below it for its global base, fine-histograms
// 128 bins, scans, writes row_ptr, scatters to col.
// ---------------------------------------------------------------------------
__global__ __launch_bounds__(256) void bucket2(const unsigned* __restrict__ bulk,
                                               const int* __restrict__ coarseCnt,
                                               int* __restrict__ row_ptr,
                                               int* __restrict__ col,
                                               int N, int E, int nCoarse) {
    __shared__ unsigned pay[CAP];
    __shared__ int red[256];
    __shared__ int hist[128];
    __shared__ int cur[128];
    int c = blockIdx.x;
    int tid = threadIdx.x;
    int cnt = coarseCnt[c * 16];
    const unsigned* seg = bulk + (size_t)c * CAP;
    if (tid < 128) hist[tid] = 0;
    int sum = 0;
    for (int i = tid; i < c; i += 256) sum += coarseCnt[i * 16];
    red[tid] = sum;
    __syncthreads();
    for (int off = 128; off > 0; off >>= 1) {
        if (tid < off) red[tid] += red[tid + off];
        __syncthreads();
    }
    int cb = red[0];                        // exclusive coarse base
    for (int i = tid; i < cnt; i += 256) {
        unsigned v = seg[i];
        pay[i] = v;
        atomicAdd(&hist[v >> 25], 1);
    }
    __syncthreads();
    // exclusive scan of 128 fine bins (threads 0..127)
    int f = tid;
    int myCnt = (f < 128) ? hist[f] : 0;
    for (int off = 1; off < 128; off <<= 1) {
        int v = (f < 128 && f >= off) ? hist[f - off] : 0;
        __syncthreads();
        if (f < 128) hist[f] += v;
        __syncthreads();
    }
    if (f < 128) {
        int excl = hist[f] - myCnt;
        int d = (c << 7) + f;
        if (d < N) row_ptr[d] = cb + excl;
        cur[f] = cb + excl;
    }
    if (c == nCoarse - 1 && tid == 0) row_ptr[N] = E;
    __syncthreads();
    for (int i = tid; i < cnt; i += 256) {
        unsigned v = pay[i];
        int pos = atomicAdd(&cur[v >> 25], 1);
        col[pos] = (int)(v & 0x1FFFFFFu);
    }
}

// ---------------------------------------------------------------------------
// Gather v3: ONE WAVE per node; 1024-thr blocks (16 waves) to cut block
// dispatch churn (r7 occupancy stuck at 40% with 12.5K tiny blocks).
//   g = lane>>4 : edge slot (4 edges per load instruction)
//   h = lane&15 : 16B dim chunk (uint4 = 8 bf16) -> 16 lanes cover D=128
// col[] entries prefetched with ONE coalesced load, distributed via __shfl.
// Tail collapse: fast unmasked 16-edge rounds, then the ENTIRE remainder in
// ONE masked 16-edge round (was: serial 4-edge rounds + partial -> deg=30
// cost 5 latency rounds, now 2). Shfl always before divergence.
// ---------------------------------------------------------------------------
__global__ __launch_bounds__(1024) void gather_kernel(const unsigned* __restrict__ Asrc,
                                                      const int* __restrict__ col,
                                                      const int* __restrict__ row_ptr,
                                                      const unsigned* __restrict__ relb,
                                                      unsigned* __restrict__ Adst, int N) {
    int n = blockIdx.x * 16 + (threadIdx.x >> 6);
    if (n >= N) return;                      // wave-uniform exit
    int lane = threadIdx.x & 63;
    int g = lane >> 4;                       // edge slot 0..3
    int h = lane & 15;                       // dim chunk 0..15
    int beg = row_ptr[n];
    int end = row_ptr[n + 1];
    float s[8];
#pragma unroll
    for (int j = 0; j < 8; ++j) s[j] = 0.f;

    for (int base = beg; base < end; base += 64) {
        int ci = base + lane;
        unsigned cv = (unsigned)col[(ci < end) ? ci : beg];   // always in-bounds
        int m = end - base; if (m > 64) m = 64;
        int e = 0;
        // ---- fast path: full 16-edge rounds, 8 x 16B loads in flight ----
        for (; e + 16 <= m; e += 16) {
            uint4 u[4], r[4];
#pragma unroll
            for (int t = 0; t < 4; ++t) {
                unsigned c = (unsigned)__shfl((int)cv, e + 4 * t + g, 64);
                u[t] = ((const uint4*)(Asrc + (size_t)(c & 0x1FFFFu) * 128 + 64))[h];
                r[t] = ((const uint4*)(relb + (size_t)(c >> 17) * 64))[h];
            }
#pragma unroll
            for (int t = 0; t < 4; ++t) {
                s[0] += blo(u[t].x) - blo(r[t].x);
                s[1] += bhi(u[t].x) - bhi(r[t].x);
                s[2] += blo(u[t].y) - blo(r[t].y);
                s[3] += bhi(u[t].y) - bhi(r[t].y);
                s[4] += blo(u[t].z) - blo(r[t].z);
                s[5] += bhi(u[t].z) - bhi(r[t].z);
                s[6] += blo(u[t].w) - blo(r[t].w);
                s[7] += bhi(u[t].w) - bhi(r[t].w);
            }
        }
        // ---- tail: ENTIRE remainder in ONE masked 16-edge round ----
        if (e < m) {
            uint4 u[4], r[4];
            bool val[4];
#pragma unroll
            for (int t = 0; t < 4; ++t) {
                int idx = e + 4 * t + g;
                val[t] = idx < m;
                unsigned c = (unsigned)__shfl((int)cv, val[t] ? idx : 0, 64);
                if (val[t]) {
                    u[t] = ((const uint4*)(Asrc + (size_t)(c & 0x1FFFFu) * 128 + 64))[h];
                    r[t] = ((const uint4*)(relb + (size_t)(c >> 17) * 64))[h];
                }
            }
#pragma unroll
            for (int t = 0; t < 4; ++t) {
                if (val[t]) {
                    s[0] += blo(u[t].x) - blo(r[t].x);
                    s[1] += bhi(u[t].x) - bhi(r[t].x);
                    s[2] += blo(u[t].y) - blo(r[t].y);
                    s[3] += bhi(u[t].y) - bhi(r[t].y);
                    s[4] += blo(u[t].z) - blo(r[t].z);
                    s[5] += bhi(u[t].z) - bhi(r[t].z);
                    s[6] += blo(u[t].w) - blo(r[t].w);
                    s[7] += bhi(u[t].w) - bhi(r[t].w);
                }
            }
        }
    }
    // reduce across the 4 edge slots: lanes l, l^16, l^32 hold same dims
#pragma unroll
    for (int j = 0; j < 8; ++j) {
        s[j] += __shfl_xor(s[j], 16, 64);
        s[j] += __shfl_xor(s[j], 32, 64);
    }
    if (g == 0) {
        uint4 o;
        o.x = bpack(s[0], s[1]);
        o.y = bpack(s[2], s[3]);
        o.z = bpack(s[4], s[5]);
        o.w = bpack(s[6], s[7]);
        ((uint4*)(Adst + (size_t)n * 128))[h] = o;
    }
}

// ---------------------------------------------------------------------------
// MFMA node GEMM, 64-node tiles (r7-proven, byte-identical):
// out[n][j] = act( cvec[j] + sum_{k<256} A[n][k]*Wt[j][k] )
// Block: 256 thr = 4 waves x 16 nodes = 64 nodes; grid 782.
// LDS: WtS 16KB + AS 8KB = 24KB. XOR-swizzled, conflict-free b128.
// ---------------------------------------------------------------------------
__global__ __launch_bounds__(256) void node_mfma(
    const unsigned* A,                  // [N][128] uints (bf16 [N][256])
    const unsigned* __restrict__ Wt,    // [128][128] uints (bf16 [128][256])
    const float* __restrict__ cvec,
    float* outf,                        // fp32 out (layer 2) or nullptr
    unsigned* __restrict__ outb,        // bf16 x-part of next A (layer 1) or nullptr
    int do_relu, int N) {
    __shared__ unsigned WtS[128 * 32];  // 16 KB
    __shared__ unsigned AS[64 * 32];    // 8 KB
    int tid = threadIdx.x;
    int w = tid >> 6;
    int lane = tid & 63;
    int m = lane & 15;
    int quad = lane >> 4;
    int nbase = blockIdx.x * 64;

    f32x4 acc[8];
#pragma unroll
    for (int t = 0; t < 8; ++t) acc[t] = (f32x4)(0.f);

    for (int kc = 0; kc < 4; ++kc) {
        for (int i = tid; i < 1024; i += 256) {
            int j = i >> 3, q = i & 7;
            uint4 v = ((const uint4*)Wt)[j * 32 + kc * 8 + q];
            *(uint4*)&WtS[j * 32 + 4 * (q ^ (j & 7))] = v;
        }
        for (int i = tid; i < 512; i += 256) {
            int n = i >> 3, q = i & 7;
            int gn = nbase + n;
            uint4 v = make_uint4(0u, 0u, 0u, 0u);
            if (gn < N) v = ((const uint4*)A)[(size_t)gn * 32 + kc * 8 + q];
            *(uint4*)&AS[n * 32 + 4 * (q ^ (n & 7))] = v;
        }
        __syncthreads();

#pragma unroll
        for (int s = 0; s < 2; ++s) {
            int g = s * 4 + quad;
            int r0 = w * 16 + m;
            short8 b0 = *(const short8*)&AS[r0 * 32 + 4 * (g ^ (r0 & 7))];
#pragma unroll
            for (int t = 0; t < 8; ++t) {
                int jr = t * 16 + m;
                short8 a = *(const short8*)&WtS[jr * 32 + 4 * (g ^ (jr & 7))];
                acc[t] = __builtin_amdgcn_mfma_f32_16x16x32_bf16(a, b0, acc[t], 0, 0, 0);
            }
        }
        __syncthreads();
    }

    int node = nbase + w * 16 + m;
    if (node < N) {
#pragma unroll
        for (int t = 0; t < 8; ++t) {
            float4 cv = ((const float4*)cvec)[t * 4 + quad];
            f32x4 a = acc[t];
            float v0 = a[0] + cv.x;
            float v1 = a[1] + cv.y;
            float v2 = a[2] + cv.z;
            float v3 = a[3] + cv.w;
            if (do_relu) {
                v0 = fmaxf(v0, 0.f); v1 = fmaxf(v1, 0.f);
                v2 = fmaxf(v2, 0.f); v3 = fmaxf(v3, 0.f);
            }
            if (outf) {
                ((float4*)outf)[(size_t)node * 32 + t * 4 + quad] =
                    make_float4(v0, v1, v2, v3);
            } else {
                uint2 o;
                o.x = bpack(v0, v1);
                o.y = bpack(v2, v3);
                ((uint2*)(outb + (size_t)node * 128))[32 + t * 4 + quad] = o;
            }
        }
    }
}

extern "C" void kernel_launch(void* const* d_in, const int* in_sizes, int n_in,
                              void* d_out, int out_size, void* d_ws, size_t ws_size,
                              hipStream_t stream) {
    const float* x    = (const float*)d_in[0];
    const int*   ei   = (const int*)d_in[1];
    const int*   et   = (const int*)d_in[2];
    const float* WI1  = (const float*)d_in[3];
    const float* WO1  = (const float*)d_in[4];
    const float* rel1 = (const float*)d_in[5];
    const float* b1   = (const float*)d_in[6];
    const float* WI2  = (const float*)d_in[7];
    const float* WO2  = (const float*)d_in[8];
    const float* rel2 = (const float*)d_in[9];
    const float* b2   = (const float*)d_in[10];

    const int E = in_sizes[2];          // 800000
    const int N = in_sizes[0] / D;      // 50000
    const int* src = ei;
    const int* dst = ei + E;
    const int nCoarse = (N + 127) / 128;   // 391

    // workspace layout (uints), A2 lives in d_out
    unsigned* wsu  = (unsigned*)d_ws;
    unsigned* A1   = wsu;                          // N*128 uints (25.6 MB)
    unsigned* Wt1  = A1 + (size_t)N * 128;         // 16384
    unsigned* Wt2  = Wt1 + 16384;                  // 16384
    float*    cvec1 = (float*)(Wt2 + 16384);       // 128
    float*    cvec2 = cvec1 + D;                   // 128
    unsigned* rb1  = (unsigned*)(cvec2 + D);       // 237*64
    unsigned* rb2  = rb1 + 237 * 64;               // 237*64
    int*      coarseCnt  = (int*)(rb2 + 237 * 64); // nCoarse*16 padded (64B/counter)
    int*      row_ptr    = coarseCnt + 8192;       // N+4
    int*      col        = row_ptr + N + 4;        // E
    unsigned* bulk       = (unsigned*)(col + E);   // nCoarse*CAP (4.8 MB)

    unsigned* A2 = (unsigned*)d_out;               // [N][128] uints -> fp32 out

    const int relHalf = 237 * 32;                  // float4s per rel table
    const int B1B = (E + 4095) / 4096;             // 196
    const int CB = (N * 32 + 255) / 256;           // 6250
    const int RB = (2 * relHalf + 255) / 256;      // 60

    // ---- zero coarse counters (tiny), then one mega prep dispatch ----
    hipMemsetAsync(coarseCnt, 0, 8192 * sizeof(int), stream);
    setup_mega<<<B1B + CB + 128 + 1 + RB, 256, 0, stream>>>(
        x, src, dst, et, WI1, WO1, WI2, WO2, rel1, rel2, b1, b2,
        A1, Wt1, Wt2, cvec1, cvec2, rb1, rb2,
        coarseCnt, bulk, N, E, relHalf, nCoarse);

    // ---- CSR finish (scan fused into bucket2) ----
    bucket2<<<nCoarse, 256, 0, stream>>>(bulk, coarseCnt, row_ptr, col,
                                         N, E, nCoarse);

    const int gather_blocks = (N + 15) / 16;       // 3125 (16 waves/block)
    const int node_blocks = (N + 63) / 64;         // 782

    // ---- layer 1: gather x-part of A1 -> agg part of A1; node -> x-part of A2
    gather_kernel<<<gather_blocks, 1024, 0, stream>>>(A1, col, row_ptr, rb1, A1, N);
    node_mfma<<<node_blocks, 256, 0, stream>>>(A1, Wt1, cvec1,
                                               (float*)nullptr, A2, 1, N);

    // ---- layer 2: gather x-part of A2 -> agg part of A2; node -> fp32 d_out
    gather_kernel<<<gather_blocks, 1024, 0, stream>>>(A2, col, row_ptr, rb2, A2, N);
    node_mfma<<<node_blocks, 256, 0, stream>>>(A2, Wt2, cvec2,
                                               (float*)d_out, (unsigned*)nullptr, 0, N);
}

// Round 9
// 229.061 us; speedup vs baseline: 1.0840x; 1.0840x over previous
//
#include <hip/hip_runtime.h>

#define D 128
#define CAP 3072        // coarse-bucket capacity (mean 2046, sigma ~45)

typedef __attribute__((ext_vector_type(8))) short short8;   // 8 bf16 (4 VGPRs)
typedef __attribute__((ext_vector_type(4))) float f32x4;    // MFMA acc

// bf16 helpers: packed storage = little-endian pairs in a uint (elem 2i = lo)
__device__ __forceinline__ float blo(unsigned w) { return __uint_as_float(w << 16); }
__device__ __forceinline__ float bhi(unsigned w) { return __uint_as_float(w & 0xFFFF0000u); }
__device__ __forceinline__ unsigned bpack(float a, float b) {   // RNE
    unsigned ua = __float_as_uint(a), ub = __float_as_uint(b);
    ua += 0x7FFFu + ((ua >> 16) & 1u);
    ub += 0x7FFFu + ((ub >> 16) & 1u);
    return (ua >> 16) | (ub & 0xFFFF0000u);
}

// ---------------------------------------------------------------------------
// setup_mega (r3-proven, byte-identical): ONE dispatch for prep + bucket1:
//   blocks [0, B1B)        : bucket1 (coarse sort, 4096 edges/block,
//                            64B-padded claim counters)
//   blocks [B1B, +CB)      : conv_x  (fp32 x -> bf16 x-part of A1)
//   blocks [.., +128)      : prep_w  (Wt bf16, 64 blocks per layer)
//   block  next            : prep_c  (cvec, both layers)
//   blocks [.., +RB)       : conv_rel (rel fp32 -> bf16)
// coarseCnt must be zeroed (hipMemsetAsync) before this kernel.
// ---------------------------------------------------------------------------
__global__ __launch_bounds__(256) void setup_mega(
    const float* __restrict__ x,
    const int* __restrict__ srcA, const int* __restrict__ dstA,
    const int* __restrict__ etA,
    const float* __restrict__ WI1, const float* __restrict__ WO1,
    const float* __restrict__ WI2, const float* __restrict__ WO2,
    const float* __restrict__ rel1, const float* __restrict__ rel2,
    const float* __restrict__ b1, const float* __restrict__ b2,
    unsigned* __restrict__ A1,
    unsigned* __restrict__ Wt1, unsigned* __restrict__ Wt2,
    float* __restrict__ c1, float* __restrict__ c2,
    unsigned* __restrict__ rb1, unsigned* __restrict__ rb2,
    int* __restrict__ coarseCnt, unsigned* __restrict__ bulk,
    int N, int E, int relHalf, int nCoarse) {
    int tid = threadIdx.x;
    int bx = blockIdx.x;
    const int B1B = (E + 4095) / 4096;

    if (bx < B1B) {                               // ---- bucket1 ----
        __shared__ unsigned pay[4096];
        __shared__ unsigned short ck[4096];
        __shared__ int hist[400];
        __shared__ int base[400];
        int e0 = bx * 4096;
        int cnt = E - e0; if (cnt > 4096) cnt = 4096;
        for (int i = tid; i < nCoarse; i += 256) hist[i] = 0;
        __syncthreads();
        for (int i = tid; i < cnt; i += 256) {
            int e = e0 + i;
            int d = dstA[e];
            pay[i] = (unsigned)srcA[e] | ((unsigned)etA[e] << 17) | ((unsigned)(d & 127) << 25);
            int c = d >> 7;
            ck[i] = (unsigned short)c;
            atomicAdd(&hist[c], 1);
        }
        __syncthreads();
        for (int i = tid; i < nCoarse; i += 256) {
            int h = hist[i];
            base[i] = (h > 0) ? (i * CAP + atomicAdd(&coarseCnt[i * 16], h)) : 0;
            hist[i] = 0;
        }
        __syncthreads();
        for (int i = tid; i < cnt; i += 256) {
            int c = ck[i];
            int pos = base[c] + atomicAdd(&hist[c], 1);
            bulk[pos] = pay[i];
        }
        return;
    }
    bx -= B1B;
    const int CB = (N * 32 + 255) / 256;
    if (bx < CB) {                                // ---- conv_x ----
        int idx = bx * 256 + tid;
        if (idx < N * 32) {
            int n = idx >> 5, q = idx & 31;
            float4 v = ((const float4*)x)[idx];
            uint2 o;
            o.x = bpack(v.x, v.y);
            o.y = bpack(v.z, v.w);
            *(uint2*)(A1 + (size_t)n * 128 + 64 + q * 2) = o;
        }
        return;
    }
    bx -= CB;
    if (bx < 128) {                               // ---- prep_w ----
        int layer = bx >> 6;
        const float* WI = layer ? WI2 : WI1;
        const float* WO = layer ? WO2 : WO1;
        unsigned* Wt = layer ? Wt2 : Wt1;
        int idx = (bx & 63) * 256 + tid;          // 0..16383
        int j = idx >> 7;
        int kk = idx & 127;
        int k0 = kk * 2;
        float a, b;
        if (k0 < D) {
            a = WI[j * D + k0];
            b = WI[j * D + k0 + 1];
        } else {
            int kx = k0 - D;
            a = WI[j * D + kx]     + WO[j * D + kx];
            b = WI[j * D + kx + 1] + WO[j * D + kx + 1];
        }
        Wt[idx] = bpack(a, b);
        return;
    }
    bx -= 128;
    if (bx == 0) {                                // ---- prep_c ----
        int layer = tid >> 7;
        int j = tid & (D - 1);
        const float* WI = layer ? WI2 : WI1;
        const float* b  = layer ? b2  : b1;
        const float* rl = layer ? rel2 : rel1;
        float s = b[j];
        for (int k = 0; k < D; ++k) s = fmaf(-WI[j * D + k], rl[k], s);
        (layer ? c2 : c1)[j] = s;
        return;
    }
    bx -= 1;
    {                                             // ---- conv_rel ----
        int idx = bx * 256 + tid;
        if (idx < 2 * relHalf) {
            const float* src = (idx < relHalf) ? rel1 : rel2;
            unsigned* dst = (idx < relHalf) ? rb1 : rb2;
            int k = (idx < relHalf) ? idx : idx - relHalf;
            float4 v = ((const float4*)src)[k];
            uint2 o;
            o.x = bpack(v.x, v.y);
            o.y = bpack(v.z, v.w);
            *(uint2*)(dst + (size_t)k * 2) = o;
        }
    }
}

// ---------------------------------------------------------------------------
// bucket2 (scan fused, r6/r7-proven): one block per coarse bucket. Reduces
// the padded coarse counters below it for its global base, fine-histograms
// 128 bins, scans, writes row_ptr, scatters to col.
// ---------------------------------------------------------------------------
__global__ __launch_bounds__(256) void bucket2(const unsigned* __restrict__ bulk,
                                               const int* __restrict__ coarseCnt,
                                               int* __restrict__ row_ptr,
                                               int* __restrict__ col,
                                               int N, int E, int nCoarse) {
    __shared__ unsigned pay[CAP];
    __shared__ int red[256];
    __shared__ int hist[128];
    __shared__ int cur[128];
    int c = blockIdx.x;
    int tid = threadIdx.x;
    int cnt = coarseCnt[c * 16];
    const unsigned* seg = bulk + (size_t)c * CAP;
    if (tid < 128) hist[tid] = 0;
    int sum = 0;
    for (int i = tid; i < c; i += 256) sum += coarseCnt[i * 16];
    red[tid] = sum;
    __syncthreads();
    for (int off = 128; off > 0; off >>= 1) {
        if (tid < off) red[tid] += red[tid + off];
        __syncthreads();
    }
    int cb = red[0];                        // exclusive coarse base
    for (int i = tid; i < cnt; i += 256) {
        unsigned v = seg[i];
        pay[i] = v;
        atomicAdd(&hist[v >> 25], 1);
    }
    __syncthreads();
    // exclusive scan of 128 fine bins (threads 0..127)
    int f = tid;
    int myCnt = (f < 128) ? hist[f] : 0;
    for (int off = 1; off < 128; off <<= 1) {
        int v = (f < 128 && f >= off) ? hist[f - off] : 0;
        __syncthreads();
        if (f < 128) hist[f] += v;
        __syncthreads();
    }
    if (f < 128) {
        int excl = hist[f] - myCnt;
        int d = (c << 7) + f;
        if (d < N) row_ptr[d] = cb + excl;
        cur[f] = cb + excl;
    }
    if (c == nCoarse - 1 && tid == 0) row_ptr[N] = E;
    __syncthreads();
    for (int i = tid; i < cnt; i += 256) {
        unsigned v = pay[i];
        int pos = atomicAdd(&cur[v >> 25], 1);
        col[pos] = (int)(v & 0x1FFFFFFu);
    }
}

// ---------------------------------------------------------------------------
// Gather v4: r7 structure (256-thr blocks, one wave/node -- the proven
// scheduling granularity; r8's 1024-thr blocks cost 25% residency) with ONE
// change: tail collapse. Fast unmasked 16-edge rounds, then the ENTIRE
// remainder in ONE masked 16-edge round (r7: up to 3 serial 4-edge rounds +
// partial; deg=30 cost 5 latency rounds, now 2). Shfl before divergence.
// ---------------------------------------------------------------------------
__global__ __launch_bounds__(256) void gather_kernel(const unsigned* __restrict__ Asrc,
                                                     const int* __restrict__ col,
                                                     const int* __restrict__ row_ptr,
                                                     const unsigned* __restrict__ relb,
                                                     unsigned* __restrict__ Adst, int N) {
    int n = blockIdx.x * 4 + (threadIdx.x >> 6);
    if (n >= N) return;                      // wave-uniform exit
    int lane = threadIdx.x & 63;
    int g = lane >> 4;                       // edge slot 0..3
    int h = lane & 15;                       // dim chunk 0..15
    int beg = row_ptr[n];
    int end = row_ptr[n + 1];
    float s[8];
#pragma unroll
    for (int j = 0; j < 8; ++j) s[j] = 0.f;

    for (int base = beg; base < end; base += 64) {
        int ci = base + lane;
        unsigned cv = (unsigned)col[(ci < end) ? ci : beg];   // always in-bounds
        int m = end - base; if (m > 64) m = 64;
        int e = 0;
        // ---- fast path: full 16-edge rounds, 8 x 16B loads in flight ----
        for (; e + 16 <= m; e += 16) {
            uint4 u[4], r[4];
#pragma unroll
            for (int t = 0; t < 4; ++t) {
                unsigned c = (unsigned)__shfl((int)cv, e + 4 * t + g, 64);
                u[t] = ((const uint4*)(Asrc + (size_t)(c & 0x1FFFFu) * 128 + 64))[h];
                r[t] = ((const uint4*)(relb + (size_t)(c >> 17) * 64))[h];
            }
#pragma unroll
            for (int t = 0; t < 4; ++t) {
                s[0] += blo(u[t].x) - blo(r[t].x);
                s[1] += bhi(u[t].x) - bhi(r[t].x);
                s[2] += blo(u[t].y) - blo(r[t].y);
                s[3] += bhi(u[t].y) - bhi(r[t].y);
                s[4] += blo(u[t].z) - blo(r[t].z);
                s[5] += bhi(u[t].z) - bhi(r[t].z);
                s[6] += blo(u[t].w) - blo(r[t].w);
                s[7] += bhi(u[t].w) - bhi(r[t].w);
            }
        }
        // ---- tail: ENTIRE remainder in ONE masked 16-edge round ----
        if (e < m) {
            uint4 u[4], r[4];
            bool val[4];
#pragma unroll
            for (int t = 0; t < 4; ++t) {
                int idx = e + 4 * t + g;
                val[t] = idx < m;
                unsigned c = (unsigned)__shfl((int)cv, val[t] ? idx : 0, 64);
                if (val[t]) {
                    u[t] = ((const uint4*)(Asrc + (size_t)(c & 0x1FFFFu) * 128 + 64))[h];
                    r[t] = ((const uint4*)(relb + (size_t)(c >> 17) * 64))[h];
                }
            }
#pragma unroll
            for (int t = 0; t < 4; ++t) {
                if (val[t]) {
                    s[0] += blo(u[t].x) - blo(r[t].x);
                    s[1] += bhi(u[t].x) - bhi(r[t].x);
                    s[2] += blo(u[t].y) - blo(r[t].y);
                    s[3] += bhi(u[t].y) - bhi(r[t].y);
                    s[4] += blo(u[t].z) - blo(r[t].z);
                    s[5] += bhi(u[t].z) - bhi(r[t].z);
                    s[6] += blo(u[t].w) - blo(r[t].w);
                    s[7] += bhi(u[t].w) - bhi(r[t].w);
                }
            }
        }
    }
    // reduce across the 4 edge slots: lanes l, l^16, l^32 hold same dims
#pragma unroll
    for (int j = 0; j < 8; ++j) {
        s[j] += __shfl_xor(s[j], 16, 64);
        s[j] += __shfl_xor(s[j], 32, 64);
    }
    if (g == 0) {
        uint4 o;
        o.x = bpack(s[0], s[1]);
        o.y = bpack(s[2], s[3]);
        o.z = bpack(s[4], s[5]);
        o.w = bpack(s[6], s[7]);
        ((uint4*)(Adst + (size_t)n * 128))[h] = o;
    }
}

// ---------------------------------------------------------------------------
// MFMA node GEMM, 64-node tiles (r7-proven, byte-identical):
// out[n][j] = act( cvec[j] + sum_{k<256} A[n][k]*Wt[j][k] )
// Block: 256 thr = 4 waves x 16 nodes = 64 nodes; grid 782.
// LDS: WtS 16KB + AS 8KB = 24KB. XOR-swizzled, conflict-free b128.
// ---------------------------------------------------------------------------
__global__ __launch_bounds__(256) void node_mfma(
    const unsigned* A,                  // [N][128] uints (bf16 [N][256])
    const unsigned* __restrict__ Wt,    // [128][128] uints (bf16 [128][256])
    const float* __restrict__ cvec,
    float* outf,                        // fp32 out (layer 2) or nullptr
    unsigned* __restrict__ outb,        // bf16 x-part of next A (layer 1) or nullptr
    int do_relu, int N) {
    __shared__ unsigned WtS[128 * 32];  // 16 KB
    __shared__ unsigned AS[64 * 32];    // 8 KB
    int tid = threadIdx.x;
    int w = tid >> 6;
    int lane = tid & 63;
    int m = lane & 15;
    int quad = lane >> 4;
    int nbase = blockIdx.x * 64;

    f32x4 acc[8];
#pragma unroll
    for (int t = 0; t < 8; ++t) acc[t] = (f32x4)(0.f);

    for (int kc = 0; kc < 4; ++kc) {
        for (int i = tid; i < 1024; i += 256) {
            int j = i >> 3, q = i & 7;
            uint4 v = ((const uint4*)Wt)[j * 32 + kc * 8 + q];
            *(uint4*)&WtS[j * 32 + 4 * (q ^ (j & 7))] = v;
        }
        for (int i = tid; i < 512; i += 256) {
            int n = i >> 3, q = i & 7;
            int gn = nbase + n;
            uint4 v = make_uint4(0u, 0u, 0u, 0u);
            if (gn < N) v = ((const uint4*)A)[(size_t)gn * 32 + kc * 8 + q];
            *(uint4*)&AS[n * 32 + 4 * (q ^ (n & 7))] = v;
        }
        __syncthreads();

#pragma unroll
        for (int s = 0; s < 2; ++s) {
            int g = s * 4 + quad;
            int r0 = w * 16 + m;
            short8 b0 = *(const short8*)&AS[r0 * 32 + 4 * (g ^ (r0 & 7))];
#pragma unroll
            for (int t = 0; t < 8; ++t) {
                int jr = t * 16 + m;
                short8 a = *(const short8*)&WtS[jr * 32 + 4 * (g ^ (jr & 7))];
                acc[t] = __builtin_amdgcn_mfma_f32_16x16x32_bf16(a, b0, acc[t], 0, 0, 0);
            }
        }
        __syncthreads();
    }

    int node = nbase + w * 16 + m;
    if (node < N) {
#pragma unroll
        for (int t = 0; t < 8; ++t) {
            float4 cv = ((const float4*)cvec)[t * 4 + quad];
            f32x4 a = acc[t];
            float v0 = a[0] + cv.x;
            float v1 = a[1] + cv.y;
            float v2 = a[2] + cv.z;
            float v3 = a[3] + cv.w;
            if (do_relu) {
                v0 = fmaxf(v0, 0.f); v1 = fmaxf(v1, 0.f);
                v2 = fmaxf(v2, 0.f); v3 = fmaxf(v3, 0.f);
            }
            if (outf) {
                ((float4*)outf)[(size_t)node * 32 + t * 4 + quad] =
                    make_float4(v0, v1, v2, v3);
            } else {
                uint2 o;
                o.x = bpack(v0, v1);
                o.y = bpack(v2, v3);
                ((uint2*)(outb + (size_t)node * 128))[32 + t * 4 + quad] = o;
            }
        }
    }
}

extern "C" void kernel_launch(void* const* d_in, const int* in_sizes, int n_in,
                              void* d_out, int out_size, void* d_ws, size_t ws_size,
                              hipStream_t stream) {
    const float* x    = (const float*)d_in[0];
    const int*   ei   = (const int*)d_in[1];
    const int*   et   = (const int*)d_in[2];
    const float* WI1  = (const float*)d_in[3];
    const float* WO1  = (const float*)d_in[4];
    const float* rel1 = (const float*)d_in[5];
    const float* b1   = (const float*)d_in[6];
    const float* WI2  = (const float*)d_in[7];
    const float* WO2  = (const float*)d_in[8];
    const float* rel2 = (const float*)d_in[9];
    const float* b2   = (const float*)d_in[10];

    const int E = in_sizes[2];          // 800000
    const int N = in_sizes[0] / D;      // 50000
    const int* src = ei;
    const int* dst = ei + E;
    const int nCoarse = (N + 127) / 128;   // 391

    // workspace layout (uints), A2 lives in d_out
    unsigned* wsu  = (unsigned*)d_ws;
    unsigned* A1   = wsu;                          // N*128 uints (25.6 MB)
    unsigned* Wt1  = A1 + (size_t)N * 128;         // 16384
    unsigned* Wt2  = Wt1 + 16384;                  // 16384
    float*    cvec1 = (float*)(Wt2 + 16384);       // 128
    float*    cvec2 = cvec1 + D;                   // 128
    unsigned* rb1  = (unsigned*)(cvec2 + D);       // 237*64
    unsigned* rb2  = rb1 + 237 * 64;               // 237*64
    int*      coarseCnt  = (int*)(rb2 + 237 * 64); // nCoarse*16 padded (64B/counter)
    int*      row_ptr    = coarseCnt + 8192;       // N+4
    int*      col        = row_ptr + N + 4;        // E
    unsigned* bulk       = (unsigned*)(col + E);   // nCoarse*CAP (4.8 MB)

    unsigned* A2 = (unsigned*)d_out;               // [N][128] uints -> fp32 out

    const int relHalf = 237 * 32;                  // float4s per rel table
    const int B1B = (E + 4095) / 4096;             // 196
    const int CB = (N * 32 + 255) / 256;           // 6250
    const int RB = (2 * relHalf + 255) / 256;      // 60

    // ---- zero coarse counters (tiny), then one mega prep dispatch ----
    hipMemsetAsync(coarseCnt, 0, 8192 * sizeof(int), stream);
    setup_mega<<<B1B + CB + 128 + 1 + RB, 256, 0, stream>>>(
        x, src, dst, et, WI1, WO1, WI2, WO2, rel1, rel2, b1, b2,
        A1, Wt1, Wt2, cvec1, cvec2, rb1, rb2,
        coarseCnt, bulk, N, E, relHalf, nCoarse);

    // ---- CSR finish (scan fused into bucket2) ----
    bucket2<<<nCoarse, 256, 0, stream>>>(bulk, coarseCnt, row_ptr, col,
                                         N, E, nCoarse);

    const int gather_blocks = (N + 3) / 4;         // 12500 (4 waves/block)
    const int node_blocks = (N + 63) / 64;         // 782

    // ---- layer 1: gather x-part of A1 -> agg part of A1; node -> x-part of A2
    gather_kernel<<<gather_blocks, 256, 0, stream>>>(A1, col, row_ptr, rb1, A1, N);
    node_mfma<<<node_blocks, 256, 0, stream>>>(A1, Wt1, cvec1,
                                               (float*)nullptr, A2, 1, N);

    // ---- layer 2: gather x-part of A2 -> agg part of A2; node -> fp32 d_out
    gather_kernel<<<gather_blocks, 256, 0, stream>>>(A2, col, row_ptr, rb2, A2, N);
    node_mfma<<<node_blocks, 256, 0, stream>>>(A2, Wt2, cvec2,
                                               (float*)d_out, (unsigned*)nullptr, 0, N);
}

// Round 10
// 224.498 us; speedup vs baseline: 1.1061x; 1.0203x over previous
//
#include <hip/hip_runtime.h>

#define D 128
#define CAP 3072        // coarse-bucket capacity (mean 2046, sigma ~45)

typedef __attribute__((ext_vector_type(8))) short short8;   // 8 bf16 (4 VGPRs)
typedef __attribute__((ext_vector_type(4))) float f32x4;    // MFMA acc

// bf16 helpers: packed storage = little-endian pairs in a uint (elem 2i = lo)
__device__ __forceinline__ float blo(unsigned w) { return __uint_as_float(w << 16); }
__device__ __forceinline__ float bhi(unsigned w) { return __uint_as_float(w & 0xFFFF0000u); }
__device__ __forceinline__ unsigned bpack(float a, float b) {   // RNE
    unsigned ua = __float_as_uint(a), ub = __float_as_uint(b);
    ua += 0x7FFFu + ((ua >> 16) & 1u);
    ub += 0x7FFFu + ((ub >> 16) & 1u);
    return (ua >> 16) | (ub & 0xFFFF0000u);
}

// ---------------------------------------------------------------------------
// setup_mega (r3-proven, byte-identical): ONE dispatch for prep + bucket1:
//   blocks [0, B1B)        : bucket1 (coarse sort, 4096 edges/block,
//                            64B-padded claim counters)
//   blocks [B1B, +CB)      : conv_x  (fp32 x -> bf16 x-part of A1)
//   blocks [.., +128)      : prep_w  (Wt bf16, 64 blocks per layer)
//   block  next            : prep_c  (cvec, both layers)
//   blocks [.., +RB)       : conv_rel (rel fp32 -> bf16)
// coarseCnt must be zeroed (hipMemsetAsync) before this kernel.
// ---------------------------------------------------------------------------
__global__ __launch_bounds__(256) void setup_mega(
    const float* __restrict__ x,
    const int* __restrict__ srcA, const int* __restrict__ dstA,
    const int* __restrict__ etA,
    const float* __restrict__ WI1, const float* __restrict__ WO1,
    const float* __restrict__ WI2, const float* __restrict__ WO2,
    const float* __restrict__ rel1, const float* __restrict__ rel2,
    const float* __restrict__ b1, const float* __restrict__ b2,
    unsigned* __restrict__ A1,
    unsigned* __restrict__ Wt1, unsigned* __restrict__ Wt2,
    float* __restrict__ c1, float* __restrict__ c2,
    unsigned* __restrict__ rb1, unsigned* __restrict__ rb2,
    int* __restrict__ coarseCnt, unsigned* __restrict__ bulk,
    int N, int E, int relHalf, int nCoarse) {
    int tid = threadIdx.x;
    int bx = blockIdx.x;
    const int B1B = (E + 4095) / 4096;

    if (bx < B1B) {                               // ---- bucket1 ----
        __shared__ unsigned pay[4096];
        __shared__ unsigned short ck[4096];
        __shared__ int hist[400];
        __shared__ int base[400];
        int e0 = bx * 4096;
        int cnt = E - e0; if (cnt > 4096) cnt = 4096;
        for (int i = tid; i < nCoarse; i += 256) hist[i] = 0;
        __syncthreads();
        for (int i = tid; i < cnt; i += 256) {
            int e = e0 + i;
            int d = dstA[e];
            pay[i] = (unsigned)srcA[e] | ((unsigned)etA[e] << 17) | ((unsigned)(d & 127) << 25);
            int c = d >> 7;
            ck[i] = (unsigned short)c;
            atomicAdd(&hist[c], 1);
        }
        __syncthreads();
        for (int i = tid; i < nCoarse; i += 256) {
            int h = hist[i];
            base[i] = (h > 0) ? (i * CAP + atomicAdd(&coarseCnt[i * 16], h)) : 0;
            hist[i] = 0;
        }
        __syncthreads();
        for (int i = tid; i < cnt; i += 256) {
            int c = ck[i];
            int pos = base[c] + atomicAdd(&hist[c], 1);
            bulk[pos] = pay[i];
        }
        return;
    }
    bx -= B1B;
    const int CB = (N * 32 + 255) / 256;
    if (bx < CB) {                                // ---- conv_x ----
        int idx = bx * 256 + tid;
        if (idx < N * 32) {
            int n = idx >> 5, q = idx & 31;
            float4 v = ((const float4*)x)[idx];
            uint2 o;
            o.x = bpack(v.x, v.y);
            o.y = bpack(v.z, v.w);
            *(uint2*)(A1 + (size_t)n * 128 + 64 + q * 2) = o;
        }
        return;
    }
    bx -= CB;
    if (bx < 128) {                               // ---- prep_w ----
        int layer = bx >> 6;
        const float* WI = layer ? WI2 : WI1;
        const float* WO = layer ? WO2 : WO1;
        unsigned* Wt = layer ? Wt2 : Wt1;
        int idx = (bx & 63) * 256 + tid;          // 0..16383
        int j = idx >> 7;
        int kk = idx & 127;
        int k0 = kk * 2;
        float a, b;
        if (k0 < D) {
            a = WI[j * D + k0];
            b = WI[j * D + k0 + 1];
        } else {
            int kx = k0 - D;
            a = WI[j * D + kx]     + WO[j * D + kx];
            b = WI[j * D + kx + 1] + WO[j * D + kx + 1];
        }
        Wt[idx] = bpack(a, b);
        return;
    }
    bx -= 128;
    if (bx == 0) {                                // ---- prep_c ----
        int layer = tid >> 7;
        int j = tid & (D - 1);
        const float* WI = layer ? WI2 : WI1;
        const float* b  = layer ? b2  : b1;
        const float* rl = layer ? rel2 : rel1;
        float s = b[j];
        for (int k = 0; k < D; ++k) s = fmaf(-WI[j * D + k], rl[k], s);
        (layer ? c2 : c1)[j] = s;
        return;
    }
    bx -= 1;
    {                                             // ---- conv_rel ----
        int idx = bx * 256 + tid;
        if (idx < 2 * relHalf) {
            const float* src = (idx < relHalf) ? rel1 : rel2;
            unsigned* dst = (idx < relHalf) ? rb1 : rb2;
            int k = (idx < relHalf) ? idx : idx - relHalf;
            float4 v = ((const float4*)src)[k];
            uint2 o;
            o.x = bpack(v.x, v.y);
            o.y = bpack(v.z, v.w);
            *(uint2*)(dst + (size_t)k * 2) = o;
        }
    }
}

// ---------------------------------------------------------------------------
// bucket2 (scan fused, r6/r7-proven): one block per coarse bucket. Reduces
// the padded coarse counters below it for its global base, fine-histograms
// 128 bins, scans, writes row_ptr, scatters to col.
// ---------------------------------------------------------------------------
__global__ __launch_bounds__(256) void bucket2(const unsigned* __restrict__ bulk,
                                               const int* __restrict__ coarseCnt,
                                               int* __restrict__ row_ptr,
                                               int* __restrict__ col,
                                               int N, int E, int nCoarse) {
    __shared__ unsigned pay[CAP];
    __shared__ int red[256];
    __shared__ int hist[128];
    __shared__ int cur[128];
    int c = blockIdx.x;
    int tid = threadIdx.x;
    int cnt = coarseCnt[c * 16];
    const unsigned* seg = bulk + (size_t)c * CAP;
    if (tid < 128) hist[tid] = 0;
    int sum = 0;
    for (int i = tid; i < c; i += 256) sum += coarseCnt[i * 16];
    red[tid] = sum;
    __syncthreads();
    for (int off = 128; off > 0; off >>= 1) {
        if (tid < off) red[tid] += red[tid + off];
        __syncthreads();
    }
    int cb = red[0];                        // exclusive coarse base
    for (int i = tid; i < cnt; i += 256) {
        unsigned v = seg[i];
        pay[i] = v;
        atomicAdd(&hist[v >> 25], 1);
    }
    __syncthreads();
    // exclusive scan of 128 fine bins (threads 0..127)
    int f = tid;
    int myCnt = (f < 128) ? hist[f] : 0;
    for (int off = 1; off < 128; off <<= 1) {
        int v = (f < 128 && f >= off) ? hist[f - off] : 0;
        __syncthreads();
        if (f < 128) hist[f] += v;
        __syncthreads();
    }
    if (f < 128) {
        int excl = hist[f] - myCnt;
        int d = (c << 7) + f;
        if (d < N) row_ptr[d] = cb + excl;
        cur[f] = cb + excl;
    }
    if (c == nCoarse - 1 && tid == 0) row_ptr[N] = E;
    __syncthreads();
    for (int i = tid; i < cnt; i += 256) {
        unsigned v = pay[i];
        int pos = atomicAdd(&cur[v >> 25], 1);
        col[pos] = (int)(v & 0x1FFFFFFu);
    }
}

// ---------------------------------------------------------------------------
// Gather v5: r7 structure (256-thr blocks, one wave/node) with a
// DIVERGENCE-FREE tail round. r9's masked tail regressed because per-slot
// `if (val)` guards exec-masked the loads -> clause broke into serialized
// exec regions. v5 instead CLAMPS the tail index (ii = min(idx, m-1)) so
// every lane issues a valid unmasked load (duplicates hit L1, free), and
// invalid slots are neutralized on the ACCUMULATE side with a 0/1 factor
// folded into an FMA (same 2 VALU/component as r7). One full-width load
// clause -> the whole tail costs ONE latency round. Expected serial
// rounds/node: r7 ~2.7 -> ~1.4 (Poisson-16 degrees).
// ---------------------------------------------------------------------------
__global__ __launch_bounds__(256) void gather_kernel(const unsigned* __restrict__ Asrc,
                                                     const int* __restrict__ col,
                                                     const int* __restrict__ row_ptr,
                                                     const unsigned* __restrict__ relb,
                                                     unsigned* __restrict__ Adst, int N) {
    int n = blockIdx.x * 4 + (threadIdx.x >> 6);
    if (n >= N) return;                      // wave-uniform exit
    int lane = threadIdx.x & 63;
    int g = lane >> 4;                       // edge slot 0..3
    int h = lane & 15;                       // dim chunk 0..15
    int beg = row_ptr[n];
    int end = row_ptr[n + 1];
    float s[8];
#pragma unroll
    for (int j = 0; j < 8; ++j) s[j] = 0.f;

    for (int base = beg; base < end; base += 64) {
        int ci = base + lane;
        unsigned cv = (unsigned)col[(ci < end) ? ci : beg];   // always in-bounds
        int m = end - base; if (m > 64) m = 64;
        int e = 0;
        // ---- fast path: full 16-edge rounds, 8 x 16B loads in flight ----
        for (; e + 16 <= m; e += 16) {
            uint4 u[4], r[4];
#pragma unroll
            for (int t = 0; t < 4; ++t) {
                unsigned c = (unsigned)__shfl((int)cv, e + 4 * t + g, 64);
                u[t] = ((const uint4*)(Asrc + (size_t)(c & 0x1FFFFu) * 128 + 64))[h];
                r[t] = ((const uint4*)(relb + (size_t)(c >> 17) * 64))[h];
            }
#pragma unroll
            for (int t = 0; t < 4; ++t) {
                s[0] += blo(u[t].x) - blo(r[t].x);
                s[1] += bhi(u[t].x) - bhi(r[t].x);
                s[2] += blo(u[t].y) - blo(r[t].y);
                s[3] += bhi(u[t].y) - bhi(r[t].y);
                s[4] += blo(u[t].z) - blo(r[t].z);
                s[5] += bhi(u[t].z) - bhi(r[t].z);
                s[6] += blo(u[t].w) - blo(r[t].w);
                s[7] += bhi(u[t].w) - bhi(r[t].w);
            }
        }
        // ---- tail: ONE unmasked clamped round, select on accumulate ----
        if (e < m) {                              // m >= 1 here
            uint4 u[4], r[4];
            float f[4];
#pragma unroll
            for (int t = 0; t < 4; ++t) {
                int idx = e + 4 * t + g;
                f[t] = (idx < m) ? 1.0f : 0.0f;
                int ii = (idx < m) ? idx : (m - 1);   // clamp: valid, unmasked
                unsigned c = (unsigned)__shfl((int)cv, ii, 64);
                u[t] = ((const uint4*)(Asrc + (size_t)(c & 0x1FFFFu) * 128 + 64))[h];
                r[t] = ((const uint4*)(relb + (size_t)(c >> 17) * 64))[h];
            }
#pragma unroll
            for (int t = 0; t < 4; ++t) {
                s[0] += f[t] * (blo(u[t].x) - blo(r[t].x));
                s[1] += f[t] * (bhi(u[t].x) - bhi(r[t].x));
                s[2] += f[t] * (blo(u[t].y) - blo(r[t].y));
                s[3] += f[t] * (bhi(u[t].y) - bhi(r[t].y));
                s[4] += f[t] * (blo(u[t].z) - blo(r[t].z));
                s[5] += f[t] * (bhi(u[t].z) - bhi(r[t].z));
                s[6] += f[t] * (blo(u[t].w) - blo(r[t].w));
                s[7] += f[t] * (bhi(u[t].w) - bhi(r[t].w));
            }
        }
    }
    // reduce across the 4 edge slots: lanes l, l^16, l^32 hold same dims
#pragma unroll
    for (int j = 0; j < 8; ++j) {
        s[j] += __shfl_xor(s[j], 16, 64);
        s[j] += __shfl_xor(s[j], 32, 64);
    }
    if (g == 0) {
        uint4 o;
        o.x = bpack(s[0], s[1]);
        o.y = bpack(s[2], s[3]);
        o.z = bpack(s[4], s[5]);
        o.w = bpack(s[6], s[7]);
        ((uint4*)(Adst + (size_t)n * 128))[h] = o;
    }
}

// ---------------------------------------------------------------------------
// MFMA node GEMM, 64-node tiles (r7-proven, byte-identical):
// out[n][j] = act( cvec[j] + sum_{k<256} A[n][k]*Wt[j][k] )
// Block: 256 thr = 4 waves x 16 nodes = 64 nodes; grid 782.
// LDS: WtS 16KB + AS 8KB = 24KB. XOR-swizzled, conflict-free b128.
// ---------------------------------------------------------------------------
__global__ __launch_bounds__(256) void node_mfma(
    const unsigned* A,                  // [N][128] uints (bf16 [N][256])
    const unsigned* __restrict__ Wt,    // [128][128] uints (bf16 [128][256])
    const float* __restrict__ cvec,
    float* outf,                        // fp32 out (layer 2) or nullptr
    unsigned* __restrict__ outb,        // bf16 x-part of next A (layer 1) or nullptr
    int do_relu, int N) {
    __shared__ unsigned WtS[128 * 32];  // 16 KB
    __shared__ unsigned AS[64 * 32];    // 8 KB
    int tid = threadIdx.x;
    int w = tid >> 6;
    int lane = tid & 63;
    int m = lane & 15;
    int quad = lane >> 4;
    int nbase = blockIdx.x * 64;

    f32x4 acc[8];
#pragma unroll
    for (int t = 0; t < 8; ++t) acc[t] = (f32x4)(0.f);

    for (int kc = 0; kc < 4; ++kc) {
        for (int i = tid; i < 1024; i += 256) {
            int j = i >> 3, q = i & 7;
            uint4 v = ((const uint4*)Wt)[j * 32 + kc * 8 + q];
            *(uint4*)&WtS[j * 32 + 4 * (q ^ (j & 7))] = v;
        }
        for (int i = tid; i < 512; i += 256) {
            int n = i >> 3, q = i & 7;
            int gn = nbase + n;
            uint4 v = make_uint4(0u, 0u, 0u, 0u);
            if (gn < N) v = ((const uint4*)A)[(size_t)gn * 32 + kc * 8 + q];
            *(uint4*)&AS[n * 32 + 4 * (q ^ (n & 7))] = v;
        }
        __syncthreads();

#pragma unroll
        for (int s = 0; s < 2; ++s) {
            int g = s * 4 + quad;
            int r0 = w * 16 + m;
            short8 b0 = *(const short8*)&AS[r0 * 32 + 4 * (g ^ (r0 & 7))];
#pragma unroll
            for (int t = 0; t < 8; ++t) {
                int jr = t * 16 + m;
                short8 a = *(const short8*)&WtS[jr * 32 + 4 * (g ^ (jr & 7))];
                acc[t] = __builtin_amdgcn_mfma_f32_16x16x32_bf16(a, b0, acc[t], 0, 0, 0);
            }
        }
        __syncthreads();
    }

    int node = nbase + w * 16 + m;
    if (node < N) {
#pragma unroll
        for (int t = 0; t < 8; ++t) {
            float4 cv = ((const float4*)cvec)[t * 4 + quad];
            f32x4 a = acc[t];
            float v0 = a[0] + cv.x;
            float v1 = a[1] + cv.y;
            float v2 = a[2] + cv.z;
            float v3 = a[3] + cv.w;
            if (do_relu) {
                v0 = fmaxf(v0, 0.f); v1 = fmaxf(v1, 0.f);
                v2 = fmaxf(v2, 0.f); v3 = fmaxf(v3, 0.f);
            }
            if (outf) {
                ((float4*)outf)[(size_t)node * 32 + t * 4 + quad] =
                    make_float4(v0, v1, v2, v3);
            } else {
                uint2 o;
                o.x = bpack(v0, v1);
                o.y = bpack(v2, v3);
                ((uint2*)(outb + (size_t)node * 128))[32 + t * 4 + quad] = o;
            }
        }
    }
}

extern "C" void kernel_launch(void* const* d_in, const int* in_sizes, int n_in,
                              void* d_out, int out_size, void* d_ws, size_t ws_size,
                              hipStream_t stream) {
    const float* x    = (const float*)d_in[0];
    const int*   ei   = (const int*)d_in[1];
    const int*   et   = (const int*)d_in[2];
    const float* WI1  = (const float*)d_in[3];
    const float* WO1  = (const float*)d_in[4];
    const float* rel1 = (const float*)d_in[5];
    const float* b1   = (const float*)d_in[6];
    const float* WI2  = (const float*)d_in[7];
    const float* WO2  = (const float*)d_in[8];
    const float* rel2 = (const float*)d_in[9];
    const float* b2   = (const float*)d_in[10];

    const int E = in_sizes[2];          // 800000
    const int N = in_sizes[0] / D;      // 50000
    const int* src = ei;
    const int* dst = ei + E;
    const int nCoarse = (N + 127) / 128;   // 391

    // workspace layout (uints), A2 lives in d_out
    unsigned* wsu  = (unsigned*)d_ws;
    unsigned* A1   = wsu;                          // N*128 uints (25.6 MB)
    unsigned* Wt1  = A1 + (size_t)N * 128;         // 16384
    unsigned* Wt2  = Wt1 + 16384;                  // 16384
    float*    cvec1 = (float*)(Wt2 + 16384);       // 128
    float*    cvec2 = cvec1 + D;                   // 128
    unsigned* rb1  = (unsigned*)(cvec2 + D);       // 237*64
    unsigned* rb2  = rb1 + 237 * 64;               // 237*64
    int*      coarseCnt  = (int*)(rb2 + 237 * 64); // nCoarse*16 padded (64B/counter)
    int*      row_ptr    = coarseCnt + 8192;       // N+4
    int*      col        = row_ptr + N + 4;        // E
    unsigned* bulk       = (unsigned*)(col + E);   // nCoarse*CAP (4.8 MB)

    unsigned* A2 = (unsigned*)d_out;               // [N][128] uints -> fp32 out

    const int relHalf = 237 * 32;                  // float4s per rel table
    const int B1B = (E + 4095) / 4096;             // 196
    const int CB = (N * 32 + 255) / 256;           // 6250
    const int RB = (2 * relHalf + 255) / 256;      // 60

    // ---- zero coarse counters (tiny), then one mega prep dispatch ----
    hipMemsetAsync(coarseCnt, 0, 8192 * sizeof(int), stream);
    setup_mega<<<B1B + CB + 128 + 1 + RB, 256, 0, stream>>>(
        x, src, dst, et, WI1, WO1, WI2, WO2, rel1, rel2, b1, b2,
        A1, Wt1, Wt2, cvec1, cvec2, rb1, rb2,
        coarseCnt, bulk, N, E, relHalf, nCoarse);

    // ---- CSR finish (scan fused into bucket2) ----
    bucket2<<<nCoarse, 256, 0, stream>>>(bulk, coarseCnt, row_ptr, col,
                                         N, E, nCoarse);

    const int gather_blocks = (N + 3) / 4;         // 12500 (4 waves/block)
    const int node_blocks = (N + 63) / 64;         // 782

    // ---- layer 1: gather x-part of A1 -> agg part of A1; node -> x-part of A2
    gather_kernel<<<gather_blocks, 256, 0, stream>>>(A1, col, row_ptr, rb1, A1, N);
    node_mfma<<<node_blocks, 256, 0, stream>>>(A1, Wt1, cvec1,
                                               (float*)nullptr, A2, 1, N);

    // ---- layer 2: gather x-part of A2 -> agg part of A2; node -> fp32 d_out
    gather_kernel<<<gather_blocks, 256, 0, stream>>>(A2, col, row_ptr, rb2, A2, N);
    node_mfma<<<node_blocks, 256, 0, stream>>>(A2, Wt2, cvec2,
                                               (float*)d_out, (unsigned*)nullptr, 0, N);
}

// Round 11
// 220.485 us; speedup vs baseline: 1.1262x; 1.0182x over previous
//
#include <hip/hip_runtime.h>

#define D 128
#define CAP 3072        // coarse-bucket capacity (mean 2046, sigma ~45)

typedef __attribute__((ext_vector_type(8))) short short8;   // 8 bf16 (4 VGPRs)
typedef __attribute__((ext_vector_type(4))) float f32x4;    // MFMA acc

// bf16 helpers: packed storage = little-endian pairs in a uint (elem 2i = lo)
__device__ __forceinline__ float blo(unsigned w) { return __uint_as_float(w << 16); }
__device__ __forceinline__ float bhi(unsigned w) { return __uint_as_float(w & 0xFFFF0000u); }
__device__ __forceinline__ unsigned bpack(float a, float b) {   // RNE
    unsigned ua = __float_as_uint(a), ub = __float_as_uint(b);
    ua += 0x7FFFu + ((ua >> 16) & 1u);
    ub += 0x7FFFu + ((ub >> 16) & 1u);
    return (ua >> 16) | (ub & 0xFFFF0000u);
}

// ---------------------------------------------------------------------------
// setup_mega (r3-proven): ONE dispatch for prep + bucket1:
//   blocks [0, B1B)        : bucket1 (coarse sort, 4096 edges/block,
//                            64B-padded claim counters)
//   blocks [B1B, +CB)      : conv_x  (fp32 x -> bf16 x-part of A1)
//   blocks [.., +128)      : prep_w  (Wt bf16, 64 blocks per layer)
//   block  next            : prep_c  (cvec, both layers)
//   blocks [.., +RB)       : conv_rel (rel fp32 -> bf16)
// coarseCnt must be zeroed (hipMemsetAsync) before this kernel.
// ---------------------------------------------------------------------------
__global__ __launch_bounds__(256) void setup_mega(
    const float* __restrict__ x,
    const int* __restrict__ srcA, const int* __restrict__ dstA,
    const int* __restrict__ etA,
    const float* __restrict__ WI1, const float* __restrict__ WO1,
    const float* __restrict__ WI2, const float* __restrict__ WO2,
    const float* __restrict__ rel1, const float* __restrict__ rel2,
    const float* __restrict__ b1, const float* __restrict__ b2,
    unsigned* __restrict__ A1,
    unsigned* __restrict__ Wt1, unsigned* __restrict__ Wt2,
    float* __restrict__ c1, float* __restrict__ c2,
    unsigned* __restrict__ rb1, unsigned* __restrict__ rb2,
    int* __restrict__ coarseCnt, unsigned* __restrict__ bulk,
    int N, int E, int relHalf, int nCoarse) {
    int tid = threadIdx.x;
    int bx = blockIdx.x;
    const int B1B = (E + 4095) / 4096;

    if (bx < B1B) {                               // ---- bucket1 ----
        __shared__ unsigned pay[4096];
        __shared__ unsigned short ck[4096];
        __shared__ int hist[400];
        __shared__ int base[400];
        int e0 = bx * 4096;
        int cnt = E - e0; if (cnt > 4096) cnt = 4096;
        for (int i = tid; i < nCoarse; i += 256) hist[i] = 0;
        __syncthreads();
        for (int i = tid; i < cnt; i += 256) {
            int e = e0 + i;
            int d = dstA[e];
            pay[i] = (unsigned)srcA[e] | ((unsigned)etA[e] << 17) | ((unsigned)(d & 127) << 25);
            int c = d >> 7;
            ck[i] = (unsigned short)c;
            atomicAdd(&hist[c], 1);
        }
        __syncthreads();
        for (int i = tid; i < nCoarse; i += 256) {
            int h = hist[i];
            base[i] = (h > 0) ? (i * CAP + atomicAdd(&coarseCnt[i * 16], h)) : 0;
            hist[i] = 0;
        }
        __syncthreads();
        for (int i = tid; i < cnt; i += 256) {
            int c = ck[i];
            int pos = base[c] + atomicAdd(&hist[c], 1);
            bulk[pos] = pay[i];
        }
        return;
    }
    bx -= B1B;
    const int CB = (N * 32 + 255) / 256;
    if (bx < CB) {                                // ---- conv_x ----
        int idx = bx * 256 + tid;
        if (idx < N * 32) {
            int n = idx >> 5, q = idx & 31;
            float4 v = ((const float4*)x)[idx];
            uint2 o;
            o.x = bpack(v.x, v.y);
            o.y = bpack(v.z, v.w);
            *(uint2*)(A1 + (size_t)n * 128 + 64 + q * 2) = o;
        }
        return;
    }
    bx -= CB;
    if (bx < 128) {                               // ---- prep_w ----
        int layer = bx >> 6;
        const float* WI = layer ? WI2 : WI1;
        const float* WO = layer ? WO2 : WO1;
        unsigned* Wt = layer ? Wt2 : Wt1;
        int idx = (bx & 63) * 256 + tid;          // 0..16383
        int j = idx >> 7;
        int kk = idx & 127;
        int k0 = kk * 2;
        float a, b;
        if (k0 < D) {
            a = WI[j * D + k0];
            b = WI[j * D + k0 + 1];
        } else {
            int kx = k0 - D;
            a = WI[j * D + kx]     + WO[j * D + kx];
            b = WI[j * D + kx + 1] + WO[j * D + kx + 1];
        }
        Wt[idx] = bpack(a, b);
        return;
    }
    bx -= 128;
    if (bx == 0) {                                // ---- prep_c ----
        int layer = tid >> 7;
        int j = tid & (D - 1);
        const float* WI = layer ? WI2 : WI1;
        const float* b  = layer ? b2  : b1;
        const float* rl = layer ? rel2 : rel1;
        float s = b[j];
        for (int k = 0; k < D; ++k) s = fmaf(-WI[j * D + k], rl[k], s);
        (layer ? c2 : c1)[j] = s;
        return;
    }
    bx -= 1;
    {                                             // ---- conv_rel ----
        int idx = bx * 256 + tid;
        if (idx < 2 * relHalf) {
            const float* src = (idx < relHalf) ? rel1 : rel2;
            unsigned* dst = (idx < relHalf) ? rb1 : rb2;
            int k = (idx < relHalf) ? idx : idx - relHalf;
            float4 v = ((const float4*)src)[k];
            uint2 o;
            o.x = bpack(v.x, v.y);
            o.y = bpack(v.z, v.w);
            *(uint2*)(dst + (size_t)k * 2) = o;
        }
    }
}

// ---------------------------------------------------------------------------
// bucket2 (scan fused, r6/r7-proven): one block per coarse bucket. Reduces
// the padded coarse counters below it for its global base, fine-histograms
// 128 bins, scans, writes row_ptr, scatters to col.
// ---------------------------------------------------------------------------
__global__ __launch_bounds__(256) void bucket2(const unsigned* __restrict__ bulk,
                                               const int* __restrict__ coarseCnt,
                                               int* __restrict__ row_ptr,
                                               int* __restrict__ col,
                                               int N, int E, int nCoarse) {
    __shared__ unsigned pay[CAP];
    __shared__ int red[256];
    __shared__ int hist[128];
    __shared__ int cur[128];
    int c = blockIdx.x;
    int tid = threadIdx.x;
    int cnt = coarseCnt[c * 16];
    const unsigned* seg = bulk + (size_t)c * CAP;
    if (tid < 128) hist[tid] = 0;
    int sum = 0;
    for (int i = tid; i < c; i += 256) sum += coarseCnt[i * 16];
    red[tid] = sum;
    __syncthreads();
    for (int off = 128; off > 0; off >>= 1) {
        if (tid < off) red[tid] += red[tid + off];
        __syncthreads();
    }
    int cb = red[0];                        // exclusive coarse base
    for (int i = tid; i < cnt; i += 256) {
        unsigned v = seg[i];
        pay[i] = v;
        atomicAdd(&hist[v >> 25], 1);
    }
    __syncthreads();
    // exclusive scan of 128 fine bins (threads 0..127)
    int f = tid;
    int myCnt = (f < 128) ? hist[f] : 0;
    for (int off = 1; off < 128; off <<= 1) {
        int v = (f < 128 && f >= off) ? hist[f - off] : 0;
        __syncthreads();
        if (f < 128) hist[f] += v;
        __syncthreads();
    }
    if (f < 128) {
        int excl = hist[f] - myCnt;
        int d = (c << 7) + f;
        if (d < N) row_ptr[d] = cb + excl;
        cur[f] = cb + excl;
    }
    if (c == nCoarse - 1 && tid == 0) row_ptr[N] = E;
    __syncthreads();
    for (int i = tid; i < cnt; i += 256) {
        unsigned v = pay[i];
        int pos = atomicAdd(&cur[v >> 25], 1);
        col[pos] = (int)(v & 0x1FFFFFFu);
    }
}

// ---------------------------------------------------------------------------
// Gather v2 (r7-proven, byte-identical — best measured of 4 tail variants):
// ONE WAVE per node, 256-thr blocks.
//   g = lane>>4 : edge slot (4 edges per load instruction)
//   h = lane&15 : 16B dim chunk (uint4 = 8 bf16) -> 16 lanes cover D=128
// col[] entries prefetched with ONE coalesced load, distributed via __shfl.
// Tail variants measured: serial-4-edge (this, 218.4 total) < clamped-FMA
// (224.5) < exec-masked (229.1) — gather is random-access-BW bound, not
// round-count bound; keep the simplest encoding.
// ---------------------------------------------------------------------------
__global__ __launch_bounds__(256) void gather_kernel(const unsigned* __restrict__ Asrc,
                                                     const int* __restrict__ col,
                                                     const int* __restrict__ row_ptr,
                                                     const unsigned* __restrict__ relb,
                                                     unsigned* __restrict__ Adst, int N) {
    int n = blockIdx.x * 4 + (threadIdx.x >> 6);
    if (n >= N) return;                      // wave-uniform exit
    int lane = threadIdx.x & 63;
    int g = lane >> 4;                       // edge slot 0..3
    int h = lane & 15;                       // dim chunk 0..15
    int beg = row_ptr[n];
    int end = row_ptr[n + 1];
    float s[8];
#pragma unroll
    for (int j = 0; j < 8; ++j) s[j] = 0.f;

    for (int base = beg; base < end; base += 64) {
        int ci = base + lane;
        unsigned cv = (unsigned)col[(ci < end) ? ci : beg];   // always in-bounds
        int m = end - base; if (m > 64) m = 64;
        int e = 0;
        // ---- fast path: full 16-edge rounds, 8 x 16B loads in flight ----
        for (; e + 16 <= m; e += 16) {
            uint4 u[4], r[4];
#pragma unroll
            for (int t = 0; t < 4; ++t) {
                unsigned c = (unsigned)__shfl((int)cv, e + 4 * t + g, 64);
                u[t] = ((const uint4*)(Asrc + (size_t)(c & 0x1FFFFu) * 128 + 64))[h];
                r[t] = ((const uint4*)(relb + (size_t)(c >> 17) * 64))[h];
            }
#pragma unroll
            for (int t = 0; t < 4; ++t) {
                s[0] += blo(u[t].x) - blo(r[t].x);
                s[1] += bhi(u[t].x) - bhi(r[t].x);
                s[2] += blo(u[t].y) - blo(r[t].y);
                s[3] += bhi(u[t].y) - bhi(r[t].y);
                s[4] += blo(u[t].z) - blo(r[t].z);
                s[5] += bhi(u[t].z) - bhi(r[t].z);
                s[6] += blo(u[t].w) - blo(r[t].w);
                s[7] += bhi(u[t].w) - bhi(r[t].w);
            }
        }
        // ---- 4-edge steps ----
        for (; e + 4 <= m; e += 4) {
            unsigned c = (unsigned)__shfl((int)cv, e + g, 64);
            uint4 u = ((const uint4*)(Asrc + (size_t)(c & 0x1FFFFu) * 128 + 64))[h];
            uint4 r = ((const uint4*)(relb + (size_t)(c >> 17) * 64))[h];
            s[0] += blo(u.x) - blo(r.x);
            s[1] += bhi(u.x) - bhi(r.x);
            s[2] += blo(u.y) - blo(r.y);
            s[3] += bhi(u.y) - bhi(r.y);
            s[4] += blo(u.z) - blo(r.z);
            s[5] += bhi(u.z) - bhi(r.z);
            s[6] += blo(u.w) - blo(r.w);
            s[7] += bhi(u.w) - bhi(r.w);
        }
        // ---- partial group (shuffle BEFORE divergence) ----
        if (e < m) {
            int idx = e + g;
            unsigned c = (unsigned)__shfl((int)cv, (idx < m) ? idx : 0, 64);
            if (idx < m) {
                uint4 u = ((const uint4*)(Asrc + (size_t)(c & 0x1FFFFu) * 128 + 64))[h];
                uint4 r = ((const uint4*)(relb + (size_t)(c >> 17) * 64))[h];
                s[0] += blo(u.x) - blo(r.x);
                s[1] += bhi(u.x) - bhi(r.x);
                s[2] += blo(u.y) - blo(r.y);
                s[3] += bhi(u.y) - bhi(r.y);
                s[4] += blo(u.z) - blo(r.z);
                s[5] += bhi(u.z) - bhi(r.z);
                s[6] += blo(u.w) - blo(r.w);
                s[7] += bhi(u.w) - bhi(r.w);
            }
        }
    }
    // reduce across the 4 edge slots: lanes l, l^16, l^32 hold same dims
#pragma unroll
    for (int j = 0; j < 8; ++j) {
        s[j] += __shfl_xor(s[j], 16, 64);
        s[j] += __shfl_xor(s[j], 32, 64);
    }
    if (g == 0) {
        uint4 o;
        o.x = bpack(s[0], s[1]);
        o.y = bpack(s[2], s[3]);
        o.z = bpack(s[4], s[5]);
        o.w = bpack(s[6], s[7]);
        ((uint4*)(Adst + (size_t)n * 128))[h] = o;
    }
}

// ---------------------------------------------------------------------------
// MFMA node GEMM, 64-node tiles (r7-proven, byte-identical):
// out[n][j] = act( cvec[j] + sum_{k<256} A[n][k]*Wt[j][k] )
// Block: 256 thr = 4 waves x 16 nodes = 64 nodes; grid 782.
// LDS: WtS 16KB + AS 8KB = 24KB. XOR-swizzled, conflict-free b128.
// ---------------------------------------------------------------------------
__global__ __launch_bounds__(256) void node_mfma(
    const unsigned* A,                  // [N][128] uints (bf16 [N][256])
    const unsigned* __restrict__ Wt,    // [128][128] uints (bf16 [128][256])
    const float* __restrict__ cvec,
    float* outf,                        // fp32 out (layer 2) or nullptr
    unsigned* __restrict__ outb,        // bf16 x-part of next A (layer 1) or nullptr
    int do_relu, int N) {
    __shared__ unsigned WtS[128 * 32];  // 16 KB
    __shared__ unsigned AS[64 * 32];    // 8 KB
    int tid = threadIdx.x;
    int w = tid >> 6;
    int lane = tid & 63;
    int m = lane & 15;
    int quad = lane >> 4;
    int nbase = blockIdx.x * 64;

    f32x4 acc[8];
#pragma unroll
    for (int t = 0; t < 8; ++t) acc[t] = (f32x4)(0.f);

    for (int kc = 0; kc < 4; ++kc) {
        for (int i = tid; i < 1024; i += 256) {
            int j = i >> 3, q = i & 7;
            uint4 v = ((const uint4*)Wt)[j * 32 + kc * 8 + q];
            *(uint4*)&WtS[j * 32 + 4 * (q ^ (j & 7))] = v;
        }
        for (int i = tid; i < 512; i += 256) {
            int n = i >> 3, q = i & 7;
            int gn = nbase + n;
            uint4 v = make_uint4(0u, 0u, 0u, 0u);
            if (gn < N) v = ((const uint4*)A)[(size_t)gn * 32 + kc * 8 + q];
            *(uint4*)&AS[n * 32 + 4 * (q ^ (n & 7))] = v;
        }
        __syncthreads();

#pragma unroll
        for (int s = 0; s < 2; ++s) {
            int g = s * 4 + quad;
            int r0 = w * 16 + m;
            short8 b0 = *(const short8*)&AS[r0 * 32 + 4 * (g ^ (r0 & 7))];
#pragma unroll
            for (int t = 0; t < 8; ++t) {
                int jr = t * 16 + m;
                short8 a = *(const short8*)&WtS[jr * 32 + 4 * (g ^ (jr & 7))];
                acc[t] = __builtin_amdgcn_mfma_f32_16x16x32_bf16(a, b0, acc[t], 0, 0, 0);
            }
        }
        __syncthreads();
    }

    int node = nbase + w * 16 + m;
    if (node < N) {
#pragma unroll
        for (int t = 0; t < 8; ++t) {
            float4 cv = ((const float4*)cvec)[t * 4 + quad];
            f32x4 a = acc[t];
            float v0 = a[0] + cv.x;
            float v1 = a[1] + cv.y;
            float v2 = a[2] + cv.z;
            float v3 = a[3] + cv.w;
            if (do_relu) {
                v0 = fmaxf(v0, 0.f); v1 = fmaxf(v1, 0.f);
                v2 = fmaxf(v2, 0.f); v3 = fmaxf(v3, 0.f);
            }
            if (outf) {
                ((float4*)outf)[(size_t)node * 32 + t * 4 + quad] =
                    make_float4(v0, v1, v2, v3);
            } else {
                uint2 o;
                o.x = bpack(v0, v1);
                o.y = bpack(v2, v3);
                ((uint2*)(outb + (size_t)node * 128))[32 + t * 4 + quad] = o;
            }
        }
    }
}

extern "C" void kernel_launch(void* const* d_in, const int* in_sizes, int n_in,
                              void* d_out, int out_size, void* d_ws, size_t ws_size,
                              hipStream_t stream) {
    const float* x    = (const float*)d_in[0];
    const int*   ei   = (const int*)d_in[1];
    const int*   et   = (const int*)d_in[2];
    const float* WI1  = (const float*)d_in[3];
    const float* WO1  = (const float*)d_in[4];
    const float* rel1 = (const float*)d_in[5];
    const float* b1   = (const float*)d_in[6];
    const float* WI2  = (const float*)d_in[7];
    const float* WO2  = (const float*)d_in[8];
    const float* rel2 = (const float*)d_in[9];
    const float* b2   = (const float*)d_in[10];

    const int E = in_sizes[2];          // 800000
    const int N = in_sizes[0] / D;      // 50000
    const int* src = ei;
    const int* dst = ei + E;
    const int nCoarse = (N + 127) / 128;   // 391

    // workspace layout (uints), A2 lives in d_out
    unsigned* wsu  = (unsigned*)d_ws;
    unsigned* A1   = wsu;                          // N*128 uints (25.6 MB)
    unsigned* Wt1  = A1 + (size_t)N * 128;         // 16384
    unsigned* Wt2  = Wt1 + 16384;                  // 16384
    float*    cvec1 = (float*)(Wt2 + 16384);       // 128
    float*    cvec2 = cvec1 + D;                   // 128
    unsigned* rb1  = (unsigned*)(cvec2 + D);       // 237*64
    unsigned* rb2  = rb1 + 237 * 64;               // 237*64
    int*      coarseCnt  = (int*)(rb2 + 237 * 64); // nCoarse*16 padded (64B/counter)
    int*      row_ptr    = coarseCnt + 8192;       // N+4
    int*      col        = row_ptr + N + 4;        // E
    unsigned* bulk       = (unsigned*)(col + E);   // nCoarse*CAP (4.8 MB)

    unsigned* A2 = (unsigned*)d_out;               // [N][128] uints -> fp32 out

    const int relHalf = 237 * 32;                  // float4s per rel table
    const int B1B = (E + 4095) / 4096;             // 196
    const int CB = (N * 32 + 255) / 256;           // 6250
    const int RB = (2 * relHalf + 255) / 256;      // 60

    // ---- zero coarse counters (tiny), then one mega prep dispatch ----
    hipMemsetAsync(coarseCnt, 0, 8192 * sizeof(int), stream);
    setup_mega<<<B1B + CB + 128 + 1 + RB, 256, 0, stream>>>(
        x, src, dst, et, WI1, WO1, WI2, WO2, rel1, rel2, b1, b2,
        A1, Wt1, Wt2, cvec1, cvec2, rb1, rb2,
        coarseCnt, bulk, N, E, relHalf, nCoarse);

    // ---- CSR finish (scan fused into bucket2) ----
    bucket2<<<nCoarse, 256, 0, stream>>>(bulk, coarseCnt, row_ptr, col,
                                         N, E, nCoarse);

    const int gather_blocks = (N + 3) / 4;         // 12500 (4 waves/block)
    const int node_blocks = (N + 63) / 64;         // 782

    // ---- layer 1: gather x-part of A1 -> agg part of A1; node -> x-part of A2
    gather_kernel<<<gather_blocks, 256, 0, stream>>>(A1, col, row_ptr, rb1, A1, N);
    node_mfma<<<node_blocks, 256, 0, stream>>>(A1, Wt1, cvec1,
                                               (float*)nullptr, A2, 1, N);

    // ---- layer 2: gather x-part of A2 -> agg part of A2; node -> fp32 d_out
    gather_kernel<<<gather_blocks, 256, 0, stream>>>(A2, col, row_ptr, rb2, A2, N);
    node_mfma<<<node_blocks, 256, 0, stream>>>(A2, Wt2, cvec2,
                                               (float*)d_out, (unsigned*)nullptr, 0, N);
}